// Round 5
// baseline (197.579 us; speedup 1.0000x reference)
//
#include <hip/hip_runtime.h>

#define SEQ    8192
#define NPOS   256            // computed rows per tile per layer
#define S_TILE 244            // valid output positions (NPOS - 12 shrink)
#define CSH    4096           // chunk stride in halves: 256 rows x 16 halves (32B/row)
#define NTHR   512            // 8 waves; wave w owns positions w*32 .. w*32+31
#define NREC   33             // A-records: L0:1 (tap-packed), L1:6, L2:10, L3:14, MLP:2
#define BN_HALFOFF (NREC*512) // float area offset (halves) inside d_ws

typedef __attribute__((ext_vector_type(8)))  _Float16 half8;
typedef __attribute__((ext_vector_type(16))) float    f32x16;
typedef unsigned int u32;
typedef __attribute__((ext_vector_type(4))) u32 u32x4;

__device__ __forceinline__ int uni(int v){ return __builtin_amdgcn_readfirstlane(v); }

__device__ __forceinline__ u32 pkh2(float a, float b){
    union { _Float16 h[2]; u32 u; } v;
    v.h[0] = (_Float16)a; v.h[1] = (_Float16)b; return v.u;
}

// Unrolled (compile-time K) bias fold: sum_ci (sum_tap W[co][ci][tap]) * t_prev[ci].
template<int K>
__device__ __forceinline__ float fold_bias(const float* __restrict__ W, int co,
    const float* __restrict__ gp, const float* __restrict__ bbp,
    const float* __restrict__ rmp, const float* __restrict__ rvp)
{
    float acc = 0.f;
#pragma unroll
    for (int ci = 0; ci < 32; ++ci) {
        float sp = gp[ci] * rsqrtf(rvp[ci] + 1e-5f);
        float tp = bbp[ci] - rmp[ci]*sp;
        float wsum = 0.f;
#pragma unroll
        for (int tap = 0; tap < K; ++tap) wsum += W[(co*32 + ci)*K + tap];
        acc += wsum * tp;
    }
    return acc;
}

// ---------------- prep ----------------
// A-records for mfma_f32_32x32x16_f16: A[m=co=lane&31][k=(lane>>5)*8+j].
//  rec 0      : L0 tap-packed: k = tap*4+ci (k<12), W0 raw. k>=12 -> 0.
//  rec 1..6   : L1 (tap,cib): W1[co][ci=cib*16+k'] * s0[ci]
//  rec 7..16  : L2 with s1;  rec 17..30: L3 with s2
//  rec 31..32 : MLP: fw1[co][ci]*s3[ci] for co<16, rows 16..31 zero.
// Float area: [4][32]{bias', oob_const} then fb1'[16].
extern "C" __global__ void prep_kernel(
    const float* w0, const float* w1, const float* w2, const float* w3,
    const float* b0, const float* g0, const float* bb0, const float* rm0, const float* rv0,
    const float* b1, const float* g1, const float* bb1, const float* rm1, const float* rv1,
    const float* b2, const float* g2, const float* bb2, const float* rm2, const float* rv2,
    const float* b3, const float* g3, const float* bb3, const float* rm3, const float* rv3,
    const float* fw1, const float* fb1, _Float16* ws)
{
    const int tid = threadIdx.x;
    const int rec = blockIdx.x;
    if (rec < NREC) {
        if (tid < 64) {
            const int lane = tid, co = lane & 31, hi = lane >> 5;
            half8 h;
            if (rec == 0) {
#pragma unroll
                for (int j = 0; j < 8; ++j) {
                    int k = hi*8 + j;
                    float wv = 0.f;
                    if (k < 12) wv = w0[(co*4 + (k & 3))*3 + (k >> 2)];
                    h[j] = (_Float16)wv;
                }
            } else if (rec < 31) {
                const float* W; const float *gp, *rvp; int K, r2;
                if      (rec < 7)  { W = w1; K = 3; r2 = rec - 1;  gp = g0; rvp = rv0; }
                else if (rec < 17) { W = w2; K = 5; r2 = rec - 7;  gp = g1; rvp = rv1; }
                else               { W = w3; K = 7; r2 = rec - 17; gp = g2; rvp = rv2; }
                const int tap = r2 >> 1, cib = r2 & 1;
#pragma unroll
                for (int j = 0; j < 8; ++j) {
                    int ci = cib*16 + hi*8 + j;
                    float s = gp[ci] * rsqrtf(rvp[ci] + 1e-5f);
                    h[j] = (_Float16)(W[(co*32 + ci)*K + tap] * s);
                }
            } else {
                const int cib = rec - 31;
#pragma unroll
                for (int j = 0; j < 8; ++j) {
                    int ci = cib*16 + hi*8 + j;
                    float s = g3[ci] * rsqrtf(rv3[ci] + 1e-5f);
                    h[j] = (_Float16)((co < 16) ? fw1[co*32 + ci]*s : 0.f);
                }
            }
            *(half8*)(ws + rec*512 + lane*8) = h;
        }
    } else {
        float* fa = (float*)(ws + BN_HALFOFF);
        if (tid < 128) {
            int l = tid >> 5, co = tid & 31;
            const float *g, *bb, *rm, *rv, *bi;
            if      (l == 0) { g=g0; bb=bb0; rm=rm0; rv=rv0; bi=b0; }
            else if (l == 1) { g=g1; bb=bb1; rm=rm1; rv=rv1; bi=b1; }
            else if (l == 2) { g=g2; bb=bb2; rm=rm2; rv=rv2; bi=b2; }
            else             { g=g3; bb=bb3; rm=rm3; rv=rv3; bi=b3; }
            float s = g[co] * rsqrtf(rv[co] + 1e-5f);
            float t = bb[co] - rm[co]*s;
            float bias = bi[co];
            if      (l == 1) bias += fold_bias<3>(w1, co, g0, bb0, rm0, rv0);
            else if (l == 2) bias += fold_bias<5>(w2, co, g1, bb1, rm1, rv1);
            else if (l == 3) bias += fold_bias<7>(w3, co, g2, bb2, rm2, rv2);
            fa[(l*32 + co)*2 + 0] = bias;
            fa[(l*32 + co)*2 + 1] = -t / s;    // stored value at seq-OOB output positions
        } else if (tid < 144) {
            int hh = tid - 128;
            float acc = fb1[hh];
#pragma unroll
            for (int c = 0; c < 32; ++c) {
                float s3 = g3[c] * rsqrtf(rv3[c] + 1e-5f);
                float t3 = bb3[c] - rm3[c]*s3;
                acc += fw1[hh*32 + c] * t3;
            }
            fa[256 + hh] = acc;                // fb1'
        }
    }
}

// ---------------- conv epilogue (R2-verified, single tile) ----------------
// C/D of mfma_f32_32x32x16: col = lane&31 = pos, row(co) = (r&3)+8*(r>>2)+4*hi.
// Pack co-pairs; v_permlane32_swap exchanges hi-halves so lane (n,hi) holds
// two quads of 8 CONSECUTIVE co:  c -> co = 16c + hi*8 + (0..7). Store is one
// b128 at chunk c, row pos, halves hi*8.. -> 16-lane phase groups walk
// ascending contiguous 16B slots.
__device__ __forceinline__ void conv_epi(
    const f32x16& acc, const float2* pv,
    _Float16* outb, int s0, int doff, int pos, int hi)
{
    const bool oob = (unsigned)(s0 + doff + pos) >= SEQ;
    u32 P[4][2];
#pragma unroll
    for (int q = 0; q < 4; ++q) {
        float v[4];
#pragma unroll
        for (int i = 0; i < 4; ++i) {
            const float2 p = pv[q*4 + i];
            float r = fmaxf(acc[q*4 + i] + p.x, 0.0f);
            v[i] = oob ? p.y : r;
        }
        P[q][0] = pkh2(v[0], v[1]);
        P[q][1] = pkh2(v[2], v[3]);
    }
#pragma unroll
    for (int c = 0; c < 2; ++c) {
        u32 a0 = P[2*c][0], b0 = P[2*c+1][0];
        u32 a1 = P[2*c][1], b1 = P[2*c+1][1];
        asm("v_permlane32_swap_b32 %0, %1" : "+v"(a0), "+v"(b0));
        asm("v_permlane32_swap_b32 %0, %1" : "+v"(a1), "+v"(b1));
        u32x4 w = {a0, a1, b0, b1};
        *(u32x4*)(outb + c*CSH + pos*16 + hi*8) = w;
    }
}

// ---------------- conv layer (L1..L3), 32x32x16, R2 layout ----------------
// LDS chunk cib holds ci [16cib..16cib+15]; row = 16 halves (32B).
// B-frag lane (n,hi): 16B at cib*CSH + (P0+n+tap)*16 + hi*8 -> contiguous 1KB/wave.
template<int K, int DOFF>
__device__ __forceinline__ void conv32(
    const _Float16* __restrict__ rec, const float2* __restrict__ bo,
    const _Float16* in, _Float16* outb, int s0, int P0, int lane)
{
    const int n = lane & 31, hi = lane >> 5;
    const _Float16* bbase = in + (P0 + n)*16 + hi*8;

    // Preload bias/oob pairs BEFORE the MFMA chain (hide L2 latency under MFMAs).
    float2 pv[16];
#pragma unroll
    for (int q = 0; q < 4; ++q)
#pragma unroll
        for (int i = 0; i < 4; ++i) pv[q*4 + i] = bo[q*8 + 4*hi + i];

    f32x16 acc;
#pragma unroll
    for (int i = 0; i < 16; ++i) acc[i] = 0.f;

#pragma unroll
    for (int tap = 0; tap < K; ++tap) {
        half8 a0 = *(const half8*)(rec + (tap*2 + 0)*512 + lane*8);
        half8 a1 = *(const half8*)(rec + (tap*2 + 1)*512 + lane*8);
        half8 b0 = *(const half8*)(bbase + 0*CSH + tap*16);
        half8 b1 = *(const half8*)(bbase + 1*CSH + tap*16);
        acc = __builtin_amdgcn_mfma_f32_32x32x16_f16(a0, b0, acc, 0, 0, 0);
        acc = __builtin_amdgcn_mfma_f32_32x32x16_f16(a1, b1, acc, 0, 0, 0);
    }
    conv_epi(acc, pv, outb, s0, DOFF, P0 + n, hi);
}

// L0: tap-packed single MFMA; staged rows (chunk 0, all 16 k-halves) are B directly.
__device__ __forceinline__ void conv32L0(
    const _Float16* __restrict__ rec, const float2* __restrict__ bo,
    const _Float16* in, _Float16* outb, int s0, int P0, int lane)
{
    const int n = lane & 31, hi = lane >> 5;
    float2 pv[16];
#pragma unroll
    for (int q = 0; q < 4; ++q)
#pragma unroll
        for (int i = 0; i < 4; ++i) pv[q*4 + i] = bo[q*8 + 4*hi + i];

    half8 a = *(const half8*)(rec + lane*8);
    f32x16 acc;
#pragma unroll
    for (int i = 0; i < 16; ++i) acc[i] = 0.f;
    half8 b = *(const half8*)(in + (P0 + n)*16 + hi*8);
    acc = __builtin_amdgcn_mfma_f32_32x32x16_f16(a, b, acc, 0, 0, 0);
    conv_epi(acc, pv, outb, s0, -6, P0 + n, hi);
}

// Buffer origins: staged=s0-7(+tap in k), L0out=s0-6, L1out=s0-5, L2out=s0-3, L3=s0.
// Validity: L0 0..255, L1 0..253, L2 0..249, L3 0..243 = S_TILE-1.
// No pad rows (R2-verified aliasing): tap reads past row 255 land in the adjacent
// chunk/buffer (finite f16) or past the LDS array (clamped); they feed only MFMA
// COLUMNS (col = pos) beyond that layer's validity bound, and columns are
// independent, so garbage never reaches a kept output.
extern "C" __global__ void __launch_bounds__(NTHR, 6)
dnashape_mfma(const float* __restrict__ x, const _Float16* __restrict__ ws,
              const float* __restrict__ fw2, const float* __restrict__ fb2,
              float* __restrict__ out)
{
    __shared__ _Float16 lds[4*CSH] __attribute__((aligned(16)));  // 32768 B -> 3 blocks/CU (24 waves)
    _Float16* bufA = lds;             // 2 chunks
    _Float16* bufB = lds + 2*CSH;     // 2 chunks

    const int tid = threadIdx.x;
    const int s0  = blockIdx.x * S_TILE;
    const int b   = blockIdx.y;

    // ---- stage: row r halves[k=tap*4+ci] = x[ci][s0-7+r+tap]; halves 12..15 = 0
    if (tid < 256) {
        const float* xb = x + b*4*SEQ;
        const int r  = tid;
        const int sb = s0 - 7 + r;
        _Float16 h[16];
#pragma unroll
        for (int tap = 0; tap < 3; ++tap) {
            const int sg = sb + tap;
            const bool ok = (unsigned)sg < SEQ;
#pragma unroll
            for (int ci = 0; ci < 4; ++ci)
                h[tap*4 + ci] = (_Float16)(ok ? xb[ci*SEQ + sg] : 0.f);
        }
#pragma unroll
        for (int j = 12; j < 16; ++j) h[j] = (_Float16)0.f;
        *(half8*)(bufB + r*16)     = *(half8*)(h);
        *(half8*)(bufB + r*16 + 8) = *(half8*)(h + 8);
    }
    __syncthreads();

    const int lane = tid & 63;
    const int wv   = uni(tid >> 6);
    const int P0   = wv * 32;                 // 8 waves x one 32-pos tile each
    const float*  fa = (const float*)(ws + BN_HALFOFF);
    const float2* bo = (const float2*)fa;

    conv32L0     (ws,           bo,      bufB, bufA, s0, P0, lane);
    __syncthreads();
    conv32<3, -5>(ws + 1*512,   bo + 32, bufA, bufB, s0, P0, lane);
    __syncthreads();
    conv32<5, -3>(ws + 7*512,   bo + 64, bufB, bufA, s0, P0, lane);
    __syncthreads();
    conv32<7,  0>(ws + 17*512,  bo + 96, bufA, bufB, s0, P0, lane);
    __syncthreads();

    // ---- MLP 32 -> 16 (relu) -> 1 via one 32x32x16 pair (rows co>=16 zero).
    {
        const int n = lane & 31, hi = lane >> 5;
        half8 am0 = *(const half8*)(ws + 31*512 + lane*8);
        half8 am1 = *(const half8*)(ws + 32*512 + lane*8);
        float fb1v[8], fw2v[8];
#pragma unroll
        for (int r = 0; r < 8; ++r) {
            const int co = (r & 3) + 8*(r >> 2) + 4*hi;   // lane's valid co (<16)
            fb1v[r] = fa[256 + co];
            fw2v[r] = fw2[co];
        }
        const float fb2v = fb2[0];
        const int pos = P0 + n;
        half8 bf0 = *(const half8*)(bufB + 0*CSH + pos*16 + hi*8);
        half8 bf1 = *(const half8*)(bufB + 1*CSH + pos*16 + hi*8);
        f32x16 d;
#pragma unroll
        for (int i = 0; i < 16; ++i) d[i] = 0.f;
        d = __builtin_amdgcn_mfma_f32_32x32x16_f16(am0, bf0, d, 0, 0, 0);
        d = __builtin_amdgcn_mfma_f32_32x32x16_f16(am1, bf1, d, 0, 0, 0);
        float part = 0.f;
#pragma unroll
        for (int r = 0; r < 8; ++r)
            part += fmaxf(d[r] + fb1v[r], 0.f) * fw2v[r];
        part += __shfl_xor(part, 32, 64);   // combine hi=0 and hi=1 co-halves
        const int gpos = s0 + pos;
        if (hi == 0 && pos < S_TILE && gpos < SEQ)
            out[b*SEQ + gpos] = part + fb2v;
    }
}

extern "C" void kernel_launch(void* const* d_in, const int* in_sizes, int n_in,
                              void* d_out, int out_size, void* d_ws, size_t ws_size,
                              hipStream_t stream) {
    const float* p[29];
    for (int i = 0; i < 29; ++i) p[i] = (const float*)d_in[i];
    _Float16* ws = (_Float16*)d_ws;   // needs 33*1024 + 1088 = 34880 B

    prep_kernel<<<dim3(NREC + 1), 144, 0, stream>>>(
        p[1], p[7], p[13], p[19],
        p[2], p[3], p[4], p[5], p[6],
        p[8], p[9], p[10], p[11], p[12],
        p[14], p[15], p[16], p[17], p[18],
        p[20], p[21], p[22], p[23], p[24],
        p[25], p[26], ws);

    dim3 grid((SEQ + S_TILE - 1) / S_TILE, 128);   // 34 x 128, 1 image per block
    dnashape_mfma<<<grid, NTHR, 0, stream>>>(p[0], (const _Float16*)ws,
                                             p[27], p[28], (float*)d_out);
}

// Round 6
// 186.139 us; speedup vs baseline: 1.0615x; 1.0615x over previous
//
#include <hip/hip_runtime.h>

#define SEQ    8192
#define S_TILE 116            // valid output positions per tile (128 computed - 12 shrink)
#define NROW   134            // staged input rows (128 + halo 6)
#define CS     1088           // chunk stride in halves; holds 136 rows (128 + zero rows + reads<=133)
#define NTHR   256            // 4 waves, one image per block; wave owns 2 n-tiles
#define NREC   37             // 36 conv A-records + 1 MLP record (each 64 lanes x 16B = 1KB)
#define BN_HALFOFF (NREC*512) // float area offset (in halves) inside d_ws

typedef __attribute__((ext_vector_type(8))) _Float16 half8;
typedef __attribute__((ext_vector_type(4))) _Float16 half4v;
typedef __attribute__((ext_vector_type(4))) float    f32x4;

__device__ __forceinline__ int uni(int v){ return __builtin_amdgcn_readfirstlane(v); }

// Unrolled (compile-time K) bias fold: sum_ci (sum_tap W[co][ci][tap]) * t_prev[ci].
template<int K>
__device__ __forceinline__ float fold_bias(const float* __restrict__ W, int co,
    const float* __restrict__ gp, const float* __restrict__ bbp,
    const float* __restrict__ rmp, const float* __restrict__ rvp)
{
    float acc = 0.f;
#pragma unroll
    for (int ci = 0; ci < 32; ++ci) {
        float sp = gp[ci] * rsqrtf(rvp[ci] + 1e-5f);
        float tp = bbp[ci] - rmp[ci]*sp;
        float wsum = 0.f;
#pragma unroll
        for (int tap = 0; tap < K; ++tap) wsum += W[(co*32 + ci)*K + tap];
        acc += wsum * tp;
    }
    return acc;
}

// ---------------- prep (identical to the verified R0 version) ----------------
// A-records carry the PREVIOUS layer's BN scale folded in: rec = W[co][ci][tap]*s_prev[ci].
// Stored activations are r = relu(z + bias'); BN applied by the next layer's folded
// weights. At seq-OOB positions store -t/s so the next layer's folded math sees 0.
// fw1 folds s3; fb1' absorbs t3. Float area: [4][32]{bias', oob_const} then fb1'[16].
// Record (tap, mh): lane l holds A[m][k] = W'[co=mh*16+(l&15)][ci=(l>>4)*8+j][tap]
// (A-operand layout for mfma_f32_16x16x32: A[m=lane&15][k=quad*8+j]).
extern "C" __global__ void prep_kernel(
    const float* w0, const float* w1, const float* w2, const float* w3,
    const float* b0, const float* g0, const float* bb0, const float* rm0, const float* rv0,
    const float* b1, const float* g1, const float* bb1, const float* rm1, const float* rv1,
    const float* b2, const float* g2, const float* bb2, const float* rm2, const float* rv2,
    const float* b3, const float* g3, const float* bb3, const float* rm3, const float* rv3,
    const float* fw1, const float* fb1, _Float16* ws)
{
    const int tid = threadIdx.x;
    const int rec = blockIdx.x;
    if (rec < NREC) {
        if (tid < 64) {
            const int lane = tid;
            const float* W; const float *gp = nullptr, *rvp = nullptr; int CIN, K, r2;
            if      (rec < 6)  { W = w0;  CIN = 4;  K = 3; r2 = rec;      }
            else if (rec < 12) { W = w1;  CIN = 32; K = 3; r2 = rec - 6;  gp = g0; rvp = rv0; }
            else if (rec < 22) { W = w2;  CIN = 32; K = 5; r2 = rec - 12; gp = g1; rvp = rv1; }
            else if (rec < 36) { W = w3;  CIN = 32; K = 7; r2 = rec - 22; gp = g2; rvp = rv2; }
            else               { W = fw1; CIN = 32; K = 1; r2 = 0;        gp = g3; rvp = rv3; }
            int tap = r2 >> 1, mh = r2 & 1;
            int co  = mh*16 + (lane & 15);
            int ci0 = (lane >> 4) * 8;
            half8 h;
#pragma unroll
            for (int j = 0; j < 8; ++j) {
                int ci = ci0 + j;
                float wv = (ci < CIN) ? W[(co*CIN + ci)*K + tap] : 0.0f;
                if (gp) wv *= gp[ci & 31] * rsqrtf(rvp[ci & 31] + 1e-5f);  // s_prev
                h[j] = (_Float16)wv;
            }
            *(half8*)(ws + rec*512 + lane*8) = h;
        }
    } else {
        float* fa = (float*)(ws + BN_HALFOFF);
        if (tid < 128) {
            int l = tid >> 5, co = tid & 31;
            const float *g, *bb, *rm, *rv, *bi;
            if      (l == 0) { g=g0; bb=bb0; rm=rm0; rv=rv0; bi=b0; }
            else if (l == 1) { g=g1; bb=bb1; rm=rm1; rv=rv1; bi=b1; }
            else if (l == 2) { g=g2; bb=bb2; rm=rm2; rv=rv2; bi=b2; }
            else             { g=g3; bb=bb3; rm=rm3; rv=rv3; bi=b3; }
            float s = g[co] * rsqrtf(rv[co] + 1e-5f);
            float t = bb[co] - rm[co]*s;
            float bias = bi[co];
            if      (l == 1) bias += fold_bias<3>(w1, co, g0, bb0, rm0, rv0);
            else if (l == 2) bias += fold_bias<5>(w2, co, g1, bb1, rm1, rv1);
            else if (l == 3) bias += fold_bias<7>(w3, co, g2, bb2, rm2, rv2);
            fa[(l*32 + co)*2 + 0] = bias;
            fa[(l*32 + co)*2 + 1] = -t / s;    // stored value at seq-OOB output positions
        } else if (tid < 144) {
            int hh = tid - 128;
            float acc = fb1[hh];
#pragma unroll
            for (int c = 0; c < 32; ++c) {
                float s3 = g3[c] * rsqrtf(rv3[c] + 1e-5f);
                float t3 = bb3[c] - rm3[c]*s3;
                acc += fw1[hh*32 + c] * t3;
            }
            fa[256 + hh] = acc;                // fb1'
        }
    }
}

// ---------------- one conv layer via MFMA (R0-verified structure) ----------------
// in/out: LDS f16, 4 chunks x rows x 8 halves (chunk cb holds ci 8cb..8cb+7).
// B-frag (lane l): pos = base+(l&15)+tap, ci = (l>>4)*8+j -> one b128 at q*CS + pos*8.
// D (C/D layout): col=lane&15 -> pos, row=q*4+r -> co (within m-half).
// BC0 (layer 0): A-records zero for ci>=8 -> all quads read chunk 0 (same-address
// broadcast, conflict-free); staging never writes chunks 1-3.
// Epilogue (BN folded forward): r = relu(acc + bias'); seq-OOB -> per-co const.
template<int K, int DOFF, bool BC0>
__device__ __forceinline__ void conv_layer(
    const _Float16* __restrict__ rec, const float2* __restrict__ bo,
    const _Float16* in, _Float16* outb, int s0, int ntb, int lane)
{
    const int q = lane >> 4, n = lane & 15;
    const _Float16* bbase = in + (BC0 ? 0 : q*CS) + (ntb*16 + n)*8;

    f32x4 acc[2][2];
#pragma unroll
    for (int nt = 0; nt < 2; ++nt)
#pragma unroll
        for (int mh = 0; mh < 2; ++mh) acc[nt][mh] = (f32x4){0.f, 0.f, 0.f, 0.f};

#pragma unroll
    for (int tap = 0; tap < K; ++tap) {
        half8 a0 = *(const half8*)(rec + (tap*2 + 0)*512 + lane*8);
        half8 a1 = *(const half8*)(rec + (tap*2 + 1)*512 + lane*8);
#pragma unroll
        for (int nt = 0; nt < 2; ++nt) {
            half8 bf = *(const half8*)(bbase + nt*128 + tap*8);
            acc[nt][0] = __builtin_amdgcn_mfma_f32_16x16x32_f16(a0, bf, acc[nt][0], 0, 0, 0);
            acc[nt][1] = __builtin_amdgcn_mfma_f32_16x16x32_f16(a1, bf, acc[nt][1], 0, 0, 0);
        }
    }

#pragma unroll
    for (int nt = 0; nt < 2; ++nt) {
        int pos = (ntb + nt)*16 + n;
        bool oob = (unsigned)(s0 + DOFF + pos) >= SEQ;
#pragma unroll
        for (int mh = 0; mh < 2; ++mh) {
            int co0 = mh*16 + q*4;
            half4v hv;
#pragma unroll
            for (int r = 0; r < 4; ++r) {
                float2 p = bo[co0 + r];   // x=bias' y=oob-const
                float v = fmaxf(acc[nt][mh][r] + p.x, 0.0f);
                if (oob) v = p.y;
                hv[r] = (_Float16)v;
            }
            int cb = mh*2 + (q >> 1);
            *(half4v*)(outb + cb*CS + pos*8 + (q & 1)*4) = hv;
        }
    }
}

// Buffer origins: in=s0-7, L0out=s0-6, L1out=s0-5, L2out=s0-3, L3out=s0.
// Validity chain (valid final rows 0..115): L3 reads L2out <=121, L2 valid to 121
// (reads L1out <=125), L1 valid to 125 (reads L0out <=127), L0 valid to 127
// (reads staged <=129 < 134). Reads beyond computed rows hit zero-pad rows
// 128..135 (bufA) or leftover staged/finite data (bufB) feeding only columns
// past that layer's validity bound; MFMA columns are independent.
extern "C" __global__ void __launch_bounds__(NTHR, 8)
dnashape_mfma(const float* __restrict__ x, const _Float16* __restrict__ ws,
              const float* __restrict__ fw2, const float* __restrict__ fb2,
              float* __restrict__ out)
{
    // One image per block: 4-wave barrier groups, 17.4 KB LDS -> 8 blocks/CU
    // (32 waves/CU, 8 independent phase-desynced barrier domains per CU).
    __shared__ _Float16 bufA[4*CS];
    __shared__ _Float16 bufB[4*CS];

    const int tid  = threadIdx.x;
    const int tile = blockIdx.x;
    const int s0   = tile * S_TILE;
    const int b    = blockIdx.y;

    // Stage chunk 0: f16(x[ci 0..3]) + 4 zero-halves. L0 reads via BC0 broadcast.
    {
        const float* xb = x + b*4*SEQ;
        for (int li = tid; li < NROW; li += NTHR) {
            int sg = s0 - 7 + li;   // input origin s0-7 (halo 7)
            bool ok = (unsigned)sg < SEQ;
            float v0 = ok ? xb[0*SEQ + sg] : 0.f;
            float v1 = ok ? xb[1*SEQ + sg] : 0.f;
            float v2 = ok ? xb[2*SEQ + sg] : 0.f;
            float v3 = ok ? xb[3*SEQ + sg] : 0.f;
            half8 h0 = {(_Float16)v0, (_Float16)v1, (_Float16)v2, (_Float16)v3, 0, 0, 0, 0};
            *(half8*)(&bufB[0*CS + li*8]) = h0;
        }
        // Zero bufA halo rows 128..135 (read beyond computed range, written by none).
        if (tid < 32) {
            const half8 z8 = {0,0,0,0,0,0,0,0};
            *(half8*)(&bufA[(tid >> 3)*CS + (128 + (tid & 7))*8]) = z8;
        }
    }
    __syncthreads();

    const int lane = tid & 63;
    const int wv   = uni(tid >> 6);
    const int ntb  = wv * 2;                // wave-uniform n-tile base (2 tiles/wave)
    const float*  fa = (const float*)(ws + BN_HALFOFF);
    const float2* bo = (const float2*)fa;

    conv_layer<3, -6, true >(ws +  0*512, bo +  0, bufB, bufA, s0, ntb, lane);
    __syncthreads();
    conv_layer<3, -5, false>(ws +  6*512, bo + 32, bufA, bufB, s0, ntb, lane);
    __syncthreads();
    conv_layer<5, -3, false>(ws + 12*512, bo + 64, bufB, bufA, s0, ntb, lane);
    __syncthreads();
    conv_layer<7,  0, false>(ws + 22*512, bo + 96, bufA, bufB, s0, ntb, lane);
    __syncthreads();

    // MLP 32 -> 16 (relu) -> 1 (fw1*s3 and fb1' prefolded): one MFMA per n-tile.
    {
        const int q = lane >> 4, n = lane & 15;
        half8 am = *(const half8*)(ws + 36*512 + lane*8);
        float fb1v[4], fw2v[4];
#pragma unroll
        for (int r = 0; r < 4; ++r) { fb1v[r] = fa[256 + q*4 + r]; fw2v[r] = fw2[q*4 + r]; }
        float fb2v = fb2[0];
#pragma unroll
        for (int nt = 0; nt < 2; ++nt) {
            int pos = (ntb + nt)*16 + n;
            half8 bf = *(const half8*)(&bufB[q*CS + pos*8]);
            f32x4 d = {0.f, 0.f, 0.f, 0.f};
            d = __builtin_amdgcn_mfma_f32_16x16x32_f16(am, bf, d, 0, 0, 0);
            float part = 0.f;
#pragma unroll
            for (int r = 0; r < 4; ++r) part += fmaxf(d[r] + fb1v[r], 0.f)*fw2v[r];
            part += __shfl_xor(part, 16, 64);   // reduce across the 4 quads (h-blocks)
            part += __shfl_xor(part, 32, 64);
            if (lane < 16) {
                int g = s0 + pos;
                if (pos < S_TILE && g < SEQ) out[b*SEQ + g] = part + fb2v;
            }
        }
    }
}

extern "C" void kernel_launch(void* const* d_in, const int* in_sizes, int n_in,
                              void* d_out, int out_size, void* d_ws, size_t ws_size,
                              hipStream_t stream) {
    const float* p[29];
    for (int i = 0; i < 29; ++i) p[i] = (const float*)d_in[i];
    _Float16* ws = (_Float16*)d_ws;   // needs 37*1024 + 1088 = 38976 B

    prep_kernel<<<dim3(NREC + 1), 144, 0, stream>>>(
        p[1], p[7], p[13], p[19],
        p[2], p[3], p[4], p[5], p[6],
        p[8], p[9], p[10], p[11], p[12],
        p[14], p[15], p[16], p[17], p[18],
        p[20], p[21], p[22], p[23], p[24],
        p[25], p[26], ws);

    dim3 grid((SEQ + S_TILE - 1) / S_TILE, 128);   // 71 x 128, 1 image per block
    dnashape_mfma<<<grid, NTHR, 0, stream>>>(p[0], (const _Float16*)ws,
                                             p[27], p[28], (float*)d_out);
}

// Round 7
// 167.585 us; speedup vs baseline: 1.1790x; 1.1107x over previous
//
#include <hip/hip_runtime.h>

#define SEQ    8192
#define S_TILE 180            // valid output positions per tile (192 computed - 12 shrink)
#define NROW   198            // staged input rows (192 + halo 6)
#define CS     1608           // chunk stride in halves; holds 201 rows (192 + halo + pad)
#define NTHR   256            // 4 waves, ONE image per block; wave owns 3 n-tiles
#define NREC   37             // 36 conv A-records + 1 MLP record (each 64 lanes x 16B = 1KB)
#define BN_HALFOFF (NREC*512) // float area offset (in halves) inside d_ws

typedef __attribute__((ext_vector_type(8))) _Float16 half8;
typedef __attribute__((ext_vector_type(4))) _Float16 half4v;
typedef __attribute__((ext_vector_type(4))) float    f32x4;

__device__ __forceinline__ int uni(int v){ return __builtin_amdgcn_readfirstlane(v); }

// Unrolled (compile-time K) bias fold: sum_ci (sum_tap W[co][ci][tap]) * t_prev[ci].
template<int K>
__device__ __forceinline__ float fold_bias(const float* __restrict__ W, int co,
    const float* __restrict__ gp, const float* __restrict__ bbp,
    const float* __restrict__ rmp, const float* __restrict__ rvp)
{
    float acc = 0.f;
#pragma unroll
    for (int ci = 0; ci < 32; ++ci) {
        float sp = gp[ci] * rsqrtf(rvp[ci] + 1e-5f);
        float tp = bbp[ci] - rmp[ci]*sp;
        float wsum = 0.f;
#pragma unroll
        for (int tap = 0; tap < K; ++tap) wsum += W[(co*32 + ci)*K + tap];
        acc += wsum * tp;
    }
    return acc;
}

// ---------------- prep (identical to the verified R0 version) ----------------
// A-records carry the PREVIOUS layer's BN scale folded in: rec = W[co][ci][tap]*s_prev[ci].
// Stored activations are r = relu(z + bias'); BN applied by the next layer's folded
// weights. At seq-OOB positions store -t/s so the next layer's folded math sees 0.
// fw1 folds s3; fb1' absorbs t3. Float area: [4][32]{bias', oob_const} then fb1'[16].
// Record (tap, mh): lane l holds A[m][k] = W'[co=mh*16+(l&15)][ci=(l>>4)*8+j][tap]
// (A-operand layout for mfma_f32_16x16x32: A[m=lane&15][k=quad*8+j]).
extern "C" __global__ void prep_kernel(
    const float* w0, const float* w1, const float* w2, const float* w3,
    const float* b0, const float* g0, const float* bb0, const float* rm0, const float* rv0,
    const float* b1, const float* g1, const float* bb1, const float* rm1, const float* rv1,
    const float* b2, const float* g2, const float* bb2, const float* rm2, const float* rv2,
    const float* b3, const float* g3, const float* bb3, const float* rm3, const float* rv3,
    const float* fw1, const float* fb1, _Float16* ws)
{
    const int tid = threadIdx.x;
    const int rec = blockIdx.x;
    if (rec < NREC) {
        if (tid < 64) {
            const int lane = tid;
            const float* W; const float *gp = nullptr, *rvp = nullptr; int CIN, K, r2;
            if      (rec < 6)  { W = w0;  CIN = 4;  K = 3; r2 = rec;      }
            else if (rec < 12) { W = w1;  CIN = 32; K = 3; r2 = rec - 6;  gp = g0; rvp = rv0; }
            else if (rec < 22) { W = w2;  CIN = 32; K = 5; r2 = rec - 12; gp = g1; rvp = rv1; }
            else if (rec < 36) { W = w3;  CIN = 32; K = 7; r2 = rec - 22; gp = g2; rvp = rv2; }
            else               { W = fw1; CIN = 32; K = 1; r2 = 0;        gp = g3; rvp = rv3; }
            int tap = r2 >> 1, mh = r2 & 1;
            int co  = mh*16 + (lane & 15);
            int ci0 = (lane >> 4) * 8;
            half8 h;
#pragma unroll
            for (int j = 0; j < 8; ++j) {
                int ci = ci0 + j;
                float wv = (ci < CIN) ? W[(co*CIN + ci)*K + tap] : 0.0f;
                if (gp) wv *= gp[ci & 31] * rsqrtf(rvp[ci & 31] + 1e-5f);  // s_prev
                h[j] = (_Float16)wv;
            }
            *(half8*)(ws + rec*512 + lane*8) = h;
        }
    } else {
        float* fa = (float*)(ws + BN_HALFOFF);
        if (tid < 128) {
            int l = tid >> 5, co = tid & 31;
            const float *g, *bb, *rm, *rv, *bi;
            if      (l == 0) { g=g0; bb=bb0; rm=rm0; rv=rv0; bi=b0; }
            else if (l == 1) { g=g1; bb=bb1; rm=rm1; rv=rv1; bi=b1; }
            else if (l == 2) { g=g2; bb=bb2; rm=rm2; rv=rv2; bi=b2; }
            else             { g=g3; bb=bb3; rm=rm3; rv=rv3; bi=b3; }
            float s = g[co] * rsqrtf(rv[co] + 1e-5f);
            float t = bb[co] - rm[co]*s;
            float bias = bi[co];
            if      (l == 1) bias += fold_bias<3>(w1, co, g0, bb0, rm0, rv0);
            else if (l == 2) bias += fold_bias<5>(w2, co, g1, bb1, rm1, rv1);
            else if (l == 3) bias += fold_bias<7>(w3, co, g2, bb2, rm2, rv2);
            fa[(l*32 + co)*2 + 0] = bias;
            fa[(l*32 + co)*2 + 1] = -t / s;    // stored value at seq-OOB output positions
        } else if (tid < 144) {
            int hh = tid - 128;
            float acc = fb1[hh];
#pragma unroll
            for (int c = 0; c < 32; ++c) {
                float s3 = g3[c] * rsqrtf(rv3[c] + 1e-5f);
                float t3 = bb3[c] - rm3[c]*s3;
                acc += fw1[hh*32 + c] * t3;
            }
            fa[256 + hh] = acc;                // fb1'
        }
    }
}

// ---------------- one conv layer via MFMA (R0-verified structure) ----------------
// in/out: LDS f16, 4 chunks x rows x 8 halves (chunk cb holds ci 8cb..8cb+7).
// B-frag (lane l): pos = base+(l&15)+tap, ci = (l>>4)*8+j -> one b128 at q*CS + pos*8.
// D (C/D layout): col=lane&15 -> pos, row=q*4+r -> co (within m-half).
// BC0 (layer 0): A-records zero for ci>=8 -> all quads read chunk 0 (same-address
// broadcast, conflict-free); staging never writes chunks 1-3.
// Epilogue (BN folded forward): r = relu(acc + bias'); seq-OOB -> per-co const.
template<int K, int DOFF, bool BC0>
__device__ __forceinline__ void conv_layer(
    const _Float16* __restrict__ rec, const float2* __restrict__ bo,
    const _Float16* in, _Float16* outb, int s0, int ntb, int lane)
{
    const int q = lane >> 4, n = lane & 15;
    const _Float16* bbase = in + (BC0 ? 0 : q*CS) + (ntb*16 + n)*8;

    f32x4 acc[3][2];
#pragma unroll
    for (int nt = 0; nt < 3; ++nt)
#pragma unroll
        for (int mh = 0; mh < 2; ++mh) acc[nt][mh] = (f32x4){0.f, 0.f, 0.f, 0.f};

#pragma unroll
    for (int tap = 0; tap < K; ++tap) {
        half8 a0 = *(const half8*)(rec + (tap*2 + 0)*512 + lane*8);
        half8 a1 = *(const half8*)(rec + (tap*2 + 1)*512 + lane*8);
#pragma unroll
        for (int nt = 0; nt < 3; ++nt) {
            half8 bf = *(const half8*)(bbase + nt*128 + tap*8);
            acc[nt][0] = __builtin_amdgcn_mfma_f32_16x16x32_f16(a0, bf, acc[nt][0], 0, 0, 0);
            acc[nt][1] = __builtin_amdgcn_mfma_f32_16x16x32_f16(a1, bf, acc[nt][1], 0, 0, 0);
        }
    }

#pragma unroll
    for (int nt = 0; nt < 3; ++nt) {
        int pos = (ntb + nt)*16 + n;
        bool oob = (unsigned)(s0 + DOFF + pos) >= SEQ;
#pragma unroll
        for (int mh = 0; mh < 2; ++mh) {
            int co0 = mh*16 + q*4;
            half4v hv;
#pragma unroll
            for (int r = 0; r < 4; ++r) {
                float2 p = bo[co0 + r];   // x=bias' y=oob-const
                float v = fmaxf(acc[nt][mh][r] + p.x, 0.0f);
                if (oob) v = p.y;
                hv[r] = (_Float16)v;
            }
            int cb = mh*2 + (q >> 1);
            *(half4v*)(outb + cb*CS + pos*8 + (q & 1)*4) = hv;
        }
    }
}

// Buffer origins: in=s0-7, L0out=s0-6, L1out=s0-5, L2out=s0-3, L3out=s0.
// Validity chain (valid final rows 0..179): L3 reads L2out <=185, L2 valid to 185
// (reads L1out <=189), L1 valid to 189 (reads L0out <=191), L0 valid to 191
// (reads staged <=193 < 198). Garbage beyond is provably never consumed.
extern "C" __global__ void __launch_bounds__(NTHR, 6)
dnashape_mfma(const float* __restrict__ x, const _Float16* __restrict__ ws,
              const float* __restrict__ fw2, const float* __restrict__ fb2,
              float* __restrict__ out)
{
    // ONE image per block (vs R0's two): same per-image geometry and staging
    // amortization, but 4-wave barrier domains and 6 independent phase-desynced
    // blocks per CU (25.7 KB LDS -> 6 blocks/CU, 24 waves = R0's wave count).
    __shared__ _Float16 bufA[4*CS];
    __shared__ _Float16 bufB[4*CS];   // 25.7 KB total

    const int tid  = threadIdx.x;
    const int tile = blockIdx.x;
    const int s0   = tile * S_TILE;
    const int b    = blockIdx.y;

    // Stage chunk 0: f16(x[ci 0..3]) + 4 zero-halves. L0 reads via BC0 broadcast;
    // chunks 1-3 never touched by staging.
    {
        const float* xb = x + b*4*SEQ;
        for (int li = tid; li < NROW; li += NTHR) {
            int sg = s0 - 7 + li;   // input origin s0-7 (halo 7)
            bool ok = (unsigned)sg < SEQ;
            float v0 = ok ? xb[0*SEQ + sg] : 0.f;
            float v1 = ok ? xb[1*SEQ + sg] : 0.f;
            float v2 = ok ? xb[2*SEQ + sg] : 0.f;
            float v3 = ok ? xb[3*SEQ + sg] : 0.f;
            half8 h0 = {(_Float16)v0, (_Float16)v1, (_Float16)v2, (_Float16)v3, 0, 0, 0, 0};
            *(half8*)(&bufB[0*CS + li*8]) = h0;
        }
        // Zero bufA halo rows 192..199 (read beyond computed range, written by none).
        if (tid < 32) {
            const half8 z8 = {0,0,0,0,0,0,0,0};
            *(half8*)(&bufA[(tid >> 3)*CS + (192 + (tid & 7))*8]) = z8;
        }
    }
    __syncthreads();

    const int lane = tid & 63;
    const int wv   = uni(tid >> 6);
    const int ntb  = wv * 3;                // wave-uniform n-tile base (3 tiles/wave)
    const float*  fa = (const float*)(ws + BN_HALFOFF);
    const float2* bo = (const float2*)fa;

    conv_layer<3, -6, true >(ws +  0*512, bo +  0, bufB, bufA, s0, ntb, lane);
    __syncthreads();
    conv_layer<3, -5, false>(ws +  6*512, bo + 32, bufA, bufB, s0, ntb, lane);
    __syncthreads();
    conv_layer<5, -3, false>(ws + 12*512, bo + 64, bufB, bufA, s0, ntb, lane);
    __syncthreads();
    conv_layer<7,  0, false>(ws + 22*512, bo + 96, bufA, bufB, s0, ntb, lane);
    __syncthreads();

    // MLP 32 -> 16 (relu) -> 1 (fw1*s3 and fb1' prefolded): one MFMA per n-tile.
    {
        const int q = lane >> 4, n = lane & 15;
        half8 am = *(const half8*)(ws + 36*512 + lane*8);
        float fb1v[4], fw2v[4];
#pragma unroll
        for (int r = 0; r < 4; ++r) { fb1v[r] = fa[256 + q*4 + r]; fw2v[r] = fw2[q*4 + r]; }
        float fb2v = fb2[0];
#pragma unroll
        for (int nt = 0; nt < 3; ++nt) {
            int pos = (ntb + nt)*16 + n;
            half8 bf = *(const half8*)(&bufB[q*CS + pos*8]);
            f32x4 d = {0.f, 0.f, 0.f, 0.f};
            d = __builtin_amdgcn_mfma_f32_16x16x32_f16(am, bf, d, 0, 0, 0);
            float part = 0.f;
#pragma unroll
            for (int r = 0; r < 4; ++r) part += fmaxf(d[r] + fb1v[r], 0.f)*fw2v[r];
            part += __shfl_xor(part, 16, 64);   // reduce across the 4 quads (h-blocks)
            part += __shfl_xor(part, 32, 64);
            if (lane < 16) {
                int g = s0 + pos;
                if (pos < S_TILE && g < SEQ) out[b*SEQ + g] = part + fb2v;
            }
        }
    }
}

extern "C" void kernel_launch(void* const* d_in, const int* in_sizes, int n_in,
                              void* d_out, int out_size, void* d_ws, size_t ws_size,
                              hipStream_t stream) {
    const float* p[29];
    for (int i = 0; i < 29; ++i) p[i] = (const float*)d_in[i];
    _Float16* ws = (_Float16*)d_ws;   // needs 37*1024 + 1088 = 38976 B

    prep_kernel<<<dim3(NREC + 1), 144, 0, stream>>>(
        p[1], p[7], p[13], p[19],
        p[2], p[3], p[4], p[5], p[6],
        p[8], p[9], p[10], p[11], p[12],
        p[14], p[15], p[16], p[17], p[18],
        p[20], p[21], p[22], p[23], p[24],
        p[25], p[26], ws);

    dim3 grid((SEQ + S_TILE - 1) / S_TILE, 128);   // 46 x 128, 1 image per block
    dnashape_mfma<<<grid, NTHR, 0, stream>>>(p[0], (const _Float16*)ws,
                                             p[27], p[28], (float*)d_out);
}